// Round 22
// baseline (101.466 us; speedup 1.0000x reference)
//
#include <hip/hip_runtime.h>
#include <hip/hip_bf16.h>
#include <cstdint>

// Problem constants (fixed shapes from the reference)
#define NB 64
#define LQ 256
#define LD 512
#define HD 768
#define QD_ELEMS (NB * LQ)          // 16384
#define DD_ELEMS (NB * LD)          // 32768
#define CELEMS   (LQ * LD)          // 131072 per batch
#define CTOTAL   ((size_t)NB * CELEMS)  // 8388608

// Affine u8 encoding of K = exp(-C/cmax) in [exp(-1), 1]:
//   k8 = round((K - KOFF) / KSCL),  K ~= KOFF + KSCL*k8
#define KOFF 0.36787944117f
#define KSCL ((1.0f - 0.36787944117f) / 255.0f)

typedef __attribute__((ext_vector_type(8))) short short8;
typedef __attribute__((ext_vector_type(16))) float f32x16;

// LLVM pattern-matches these to v_cvt_f32_ubyte0..3 on gfx9xx.
static __device__ __forceinline__ float ub0(unsigned int w) {
    return (float)(w & 0xffu);
}
static __device__ __forceinline__ float ub1(unsigned int w) {
    return (float)((w >> 8) & 0xffu);
}
static __device__ __forceinline__ float ub2(unsigned int w) {
    return (float)((w >> 16) & 0xffu);
}
static __device__ __forceinline__ float ub3(unsigned int w) {
    return (float)(w >> 24);
}
static __device__ __forceinline__ float readlane_f(float v, int l) {
    return __uint_as_float((unsigned int)__builtin_amdgcn_readlane((int)__float_as_uint(v), l));
}
// f32 -> bf16 round-to-nearest-even (bit trick; inputs are finite)
static __device__ __forceinline__ unsigned short f2bf(float f) {
    unsigned int u = __float_as_uint(f);
    u += 0x7fff + ((u >> 16) & 1);
    return (unsigned short)(u >> 16);
}

// ---------------------------------------------------------------------------
// Kernel: batched GEMM via bf16 MFMA, fused row norms, DOUBLE-BUFFERED LDS.
// C[b,q,d] = 1 - (qe.de) * qinv*dinv, + per-batch max (atomic).
// 128x128 tile, 4 waves (2x2), wave tile 64x64 = 4x mfma_f32_32x32x16_bf16.
// Grid: wgid = t*64 + b (XCD pinning). R21 profile: MfmaUtil 5.5%, Occ 21%
// (2 blocks/CU, grid-limited) -> latency-bound with no TLP headroom; this
// round adds ILP: substep k+1's 16 global loads are issued BEFORE substep
// k's MFMA cluster (results land in named regs, converted+written to the
// other LDS buffer after), 1 barrier/substep. LDS 74 KB/block keeps the
// VGPR budget at 256 (2 waves/SIMD) so the ~64 in-flight regs can't spill.
// ---------------------------------------------------------------------------
#define GLOAD(H, PA0, PA1, PB0, PB1, KOF) { \
    const int idx_ = tid + (H) * 256; \
    const int r_ = idx_ >> 3, c_ = idx_ & 7; \
    const float* ap_ = Ag + (size_t)r_ * HD + (KOF) + c_ * 8; \
    const float* bp_ = Bg + (size_t)r_ * HD + (KOF) + c_ * 8; \
    PA0 = *reinterpret_cast<const float4*>(ap_); \
    PA1 = *reinterpret_cast<const float4*>(ap_ + 4); \
    PB0 = *reinterpret_cast<const float4*>(bp_); \
    PB1 = *reinterpret_cast<const float4*>(bp_ + 4); }

#define GWRITE(H, PA0, PA1, PB0, PB1, ADST, BDST, SQA, SQB) { \
    const int idx_ = tid + (H) * 256; \
    const int r_ = idx_ >> 3, c_ = idx_ & 7; \
    SQA += PA0.x * PA0.x + PA0.y * PA0.y + PA0.z * PA0.z + PA0.w * PA0.w \
         + PA1.x * PA1.x + PA1.y * PA1.y + PA1.z * PA1.z + PA1.w * PA1.w; \
    SQB += PB0.x * PB0.x + PB0.y * PB0.y + PB0.z * PB0.z + PB0.w * PB0.w \
         + PB1.x * PB1.x + PB1.y * PB1.y + PB1.z * PB1.z + PB1.w * PB1.w; \
    short8 av_, bv_; \
    av_[0] = (short)f2bf(PA0.x); av_[1] = (short)f2bf(PA0.y); \
    av_[2] = (short)f2bf(PA0.z); av_[3] = (short)f2bf(PA0.w); \
    av_[4] = (short)f2bf(PA1.x); av_[5] = (short)f2bf(PA1.y); \
    av_[6] = (short)f2bf(PA1.z); av_[7] = (short)f2bf(PA1.w); \
    bv_[0] = (short)f2bf(PB0.x); bv_[1] = (short)f2bf(PB0.y); \
    bv_[2] = (short)f2bf(PB0.z); bv_[3] = (short)f2bf(PB0.w); \
    bv_[4] = (short)f2bf(PB1.x); bv_[5] = (short)f2bf(PB1.y); \
    bv_[6] = (short)f2bf(PB1.z); bv_[7] = (short)f2bf(PB1.w); \
    const int bo_ = (r_ * 128 + c_ * 16) ^ ((r_ & 7) << 4); \
    *reinterpret_cast<short8*>((ADST) + bo_) = av_; \
    *reinterpret_cast<short8*>((BDST) + bo_) = bv_; }

__global__ __launch_bounds__(256) void gemm_mfma_kernel(
        const float* __restrict__ qe,
        const float* __restrict__ de,
        float* __restrict__ Cout,
        unsigned int* __restrict__ cmax) {
    const int wgid = blockIdx.x;
    const int b = wgid & 63;         // batch pinned to XCD (wgid%8 == b%8)
    const int t = wgid >> 6;
    const int m0 = (t >> 2) * 128;   // q-tile base (2 tiles)
    const int n0 = (t & 3) * 128;    // d-tile base (4 tiles)
    const int tid = threadIdx.x;
    const int wv = tid >> 6;
    const int lane = tid & 63;
    const int wm = (wv >> 1) * 64;
    const int wn = (wv & 1) * 64;

    __shared__ __align__(16) unsigned char AsBuf[2][128 * 128];  // 32 KB
    __shared__ __align__(16) unsigned char BsBuf[2][128 * 128];  // 32 KB
    __shared__ float sq_l[2][128][8];                            // 8 KB
    __shared__ float qinv_s[128], dinv_s[128];

    const float* Ag = qe + (size_t)b * LQ * HD + (size_t)m0 * HD;
    const float* Bg = de + (size_t)b * LD * HD + (size_t)n0 * HD;

    f32x16 acc00, acc01, acc10, acc11;
#pragma unroll
    for (int i = 0; i < 16; ++i) {
        acc00[i] = 0.f; acc01[i] = 0.f; acc10[i] = 0.f; acc11[i] = 0.f;
    }
    float asq0 = 0.f, asq1 = 0.f, asq2 = 0.f, asq3 = 0.f;
    float bsq0 = 0.f, bsq1 = 0.f, bsq2 = 0.f, bsq3 = 0.f;

    // In-flight staging registers (named; reused every iteration)
    float4 pa00, pa01, pb00, pb01;
    float4 pa10, pa11, pb10, pb11;
    float4 pa20, pa21, pb20, pb21;
    float4 pa30, pa31, pb30, pb31;

    // Prologue: stage tile 0 into buffer 0
    GLOAD(0, pa00, pa01, pb00, pb01, 0)
    GLOAD(1, pa10, pa11, pb10, pb11, 0)
    GLOAD(2, pa20, pa21, pb20, pb21, 0)
    GLOAD(3, pa30, pa31, pb30, pb31, 0)
    GWRITE(0, pa00, pa01, pb00, pb01, &AsBuf[0][0], &BsBuf[0][0], asq0, bsq0)
    GWRITE(1, pa10, pa11, pb10, pb11, &AsBuf[0][0], &BsBuf[0][0], asq1, bsq1)
    GWRITE(2, pa20, pa21, pb20, pb21, &AsBuf[0][0], &BsBuf[0][0], asq2, bsq2)
    GWRITE(3, pa30, pa31, pb30, pb31, &AsBuf[0][0], &BsBuf[0][0], asq3, bsq3)
    __syncthreads();

    const int hi = lane >> 5;
    const int la32 = lane & 31;

    for (int ks = 0; ks < HD / 64; ++ks) {           // 12 substeps
        const unsigned char* Acur = &AsBuf[ks & 1][0];
        const unsigned char* Bcur = &BsBuf[ks & 1][0];

        // Issue next tile's loads BEFORE the MFMA cluster (latency hides).
        if (ks < HD / 64 - 1) {
            const int kof = (ks + 1) * 64;
            GLOAD(0, pa00, pa01, pb00, pb01, kof)
            GLOAD(1, pa10, pa11, pb10, pb11, kof)
            GLOAD(2, pa20, pa21, pb20, pb21, kof)
            GLOAD(3, pa30, pa31, pb30, pb31, kof)
        }

#pragma unroll
        for (int k4 = 0; k4 < 4; ++k4) {
            int ra0 = wm + la32, ra1 = wm + 32 + la32;
            int rb0 = wn + la32, rb1 = wn + 32 + la32;
            short8 af0 = *reinterpret_cast<const short8*>(
                Acur + ((ra0 * 128 + k4 * 32 + hi * 16) ^ ((ra0 & 7) << 4)));
            short8 af1 = *reinterpret_cast<const short8*>(
                Acur + ((ra1 * 128 + k4 * 32 + hi * 16) ^ ((ra1 & 7) << 4)));
            short8 bf0 = *reinterpret_cast<const short8*>(
                Bcur + ((rb0 * 128 + k4 * 32 + hi * 16) ^ ((rb0 & 7) << 4)));
            short8 bf1 = *reinterpret_cast<const short8*>(
                Bcur + ((rb1 * 128 + k4 * 32 + hi * 16) ^ ((rb1 & 7) << 4)));
            acc00 = __builtin_amdgcn_mfma_f32_32x32x16_bf16(af0, bf0, acc00, 0, 0, 0);
            acc01 = __builtin_amdgcn_mfma_f32_32x32x16_bf16(af0, bf1, acc01, 0, 0, 0);
            acc10 = __builtin_amdgcn_mfma_f32_32x32x16_bf16(af1, bf0, acc10, 0, 0, 0);
            acc11 = __builtin_amdgcn_mfma_f32_32x32x16_bf16(af1, bf1, acc11, 0, 0, 0);
        }

        // Convert + write next tile into the other buffer (waits the loads).
        if (ks < HD / 64 - 1) {
            unsigned char* Anxt = &AsBuf[(ks + 1) & 1][0];
            unsigned char* Bnxt = &BsBuf[(ks + 1) & 1][0];
            GWRITE(0, pa00, pa01, pb00, pb01, Anxt, Bnxt, asq0, bsq0)
            GWRITE(1, pa10, pa11, pb10, pb11, Anxt, Bnxt, asq1, bsq1)
            GWRITE(2, pa20, pa21, pb20, pb21, Anxt, Bnxt, asq2, bsq2)
            GWRITE(3, pa30, pa31, pb30, pb31, Anxt, Bnxt, asq3, bsq3)
        }
        __syncthreads();
    }

    // Norm reduction: thread owns 4 fixed (r,c) pairs (idx = tid + h*256)
#pragma unroll
    for (int h = 0; h < 4; ++h) {
        int idx = tid + h * 256;
        int r = idx >> 3, c = idx & 7;
        float as = (h == 0) ? asq0 : (h == 1) ? asq1 : (h == 2) ? asq2 : asq3;
        float bs = (h == 0) ? bsq0 : (h == 1) ? bsq1 : (h == 2) ? bsq2 : bsq3;
        sq_l[0][r][c] = as;
        sq_l[1][r][c] = bs;
    }
    __syncthreads();
    if (tid < 128) {
        float s = sq_l[0][tid][0] + sq_l[0][tid][1] + sq_l[0][tid][2] + sq_l[0][tid][3]
                + sq_l[0][tid][4] + sq_l[0][tid][5] + sq_l[0][tid][6] + sq_l[0][tid][7];
        qinv_s[tid] = 1.0f / fmaxf(sqrtf(s), 1e-12f);
    } else {
        int r = tid - 128;
        float s = sq_l[1][r][0] + sq_l[1][r][1] + sq_l[1][r][2] + sq_l[1][r][3]
                + sq_l[1][r][4] + sq_l[1][r][5] + sq_l[1][r][6] + sq_l[1][r][7];
        dinv_s[r] = 1.0f / fmaxf(sqrtf(s), 1e-12f);
    }
    __syncthreads();

    // Epilogue: C/D layout col=lane&31, row=(reg&3)+8*(reg>>2)+4*(lane>>5)
    float lmax = -1e30f;
    float* Cb = Cout + (size_t)b * CELEMS;
    const int la = lane & 31;
    const int hi4 = (lane >> 5) * 4;
#define EPI(ACC, P, Q) { \
    int col = wn + (Q) * 32 + la; \
    float dv = dinv_s[col]; \
    _Pragma("unroll") \
    for (int i = 0; i < 16; ++i) { \
        int row = wm + (P) * 32 + (i & 3) + 8 * (i >> 2) + hi4; \
        float c = 1.0f - ACC[i] * qinv_s[row] * dv; \
        Cb[(size_t)(m0 + row) * LD + n0 + col] = c; \
        lmax = fmaxf(lmax, c); \
    } }
    EPI(acc00, 0, 0)
    EPI(acc01, 0, 1)
    EPI(acc10, 1, 0)
    EPI(acc11, 1, 1)
#undef EPI

    __shared__ float red[256];
    red[tid] = lmax;
    __syncthreads();
    for (int st = 128; st; st >>= 1) {
        if (tid < st) red[tid] = fmaxf(red[tid], red[tid + st]);
        __syncthreads();
    }
    if (tid == 0) atomicMax(cmax + b, __float_as_uint(red[0]));
}

// ---------------------------------------------------------------------------
// Kernel: K = exp(-C / cmax) quantized to affine u8 (4 elems/thread)
// Full-chip parallel (8192 blocks).
// ---------------------------------------------------------------------------
__global__ __launch_bounds__(256) void expk_kernel(const float4* __restrict__ C4,
                                                   const unsigned int* __restrict__ cmax,
                                                   unsigned int* __restrict__ K4) {
    size_t t = (size_t)blockIdx.x * 256 + threadIdx.x;  // 2097152 total
    int b = (int)(t >> 15);
    float inv = -1.0f / __uint_as_float(cmax[b]);
    const float sc = 1.0f / KSCL;
    float4 c = C4[t];
    float q0 = fminf(fmaxf((expf(c.x * inv) - KOFF) * sc, 0.f), 255.f);
    float q1 = fminf(fmaxf((expf(c.y * inv) - KOFF) * sc, 0.f), 255.f);
    float q2 = fminf(fmaxf((expf(c.z * inv) - KOFF) * sc, 0.f), 255.f);
    float q3 = fminf(fmaxf((expf(c.w * inv) - KOFF) * sc, 0.f), 255.f);
    unsigned int i0 = (unsigned int)(q0 + 0.5f);
    unsigned int i1 = (unsigned int)(q1 + 0.5f);
    unsigned int i2 = (unsigned int)(q2 + 0.5f);
    unsigned int i3 = (unsigned int)(q3 + 0.5f);
    K4[t] = i0 | (i1 << 8) | (i2 << 16) | (i3 << 24);
}

// ---------------------------------------------------------------------------
// Kernel: persistent Sinkhorn — one workgroup per batch, nit iterations.
// Whole-batch K as affine-u8 in LDS (128 KB); convergence early-exit
// (v fixed point, rel tol 1e-6); mask->distribution fused into prologue
// (K-staging DMA issued first so HBM latency hides under mask reduction).
// ---------------------------------------------------------------------------
__global__ __launch_bounds__(1024) __attribute__((amdgpu_waves_per_eu(4, 4)))
void sinkhorn_kernel(
        const unsigned char* __restrict__ Kmat,
        const float* __restrict__ qmask,
        const float* __restrict__ dmask,
        const int* __restrict__ nitp,
        float* __restrict__ uout,
        float* __restrict__ vout) {
    const int b = blockIdx.x;
    const int tid = threadIdx.x;
    const int wv = tid >> 6;       // wave 0..15
    const int lane = tid & 63;
    const int d8 = lane << 3;      // v-step column base (0..504)
    const int qbase = wv << 4;     // row base (0..240)
    const int g = lane >> 4;       // 16-lane group 0..3 (u-step row within pass)
    const int m = lane & 15;       // position within group

    __shared__ unsigned char K8[LQ][LD];   // 128 KB whole-batch K
    __shared__ float part8[8][LD];         // 16 KB partials
    __shared__ float vs[LD];               // 2 KB
    __shared__ float ulds[16][16];         // 1 KB  u[wave][row]
    __shared__ unsigned int cflag[8];      // per-wave convergence flags
    __shared__ float msum[2][16];          // mask-sum partials

    // Issue whole-batch K staging (128 KB) HBM/L2 -> LDS first (no VGPR
    // transit); its latency hides under the mask reduction below.
    {
        const unsigned char* Kg = Kmat + (size_t)b * CELEMS;
        unsigned char* lb = &K8[0][0];
#pragma unroll
        for (int j = 0; j < 8; ++j) {
            __builtin_amdgcn_global_load_lds(
                (const __attribute__((address_space(1))) unsigned int*)
                    (Kg + (size_t)wv * 8192 + j * 1024 + lane * 16),
                (__attribute__((address_space(3))) unsigned int*)
                    (lb + wv * 8192 + j * 1024),
                16, 0, 0);
        }
    }

    if (tid < LQ) ulds[tid >> 4][tid & 15] = 1.0f;
    if (tid < LD) vs[tid] = 0.f;           // "previous v" for 1st iteration

    // ---- fused mass: qdist = qmask/sum(qmask), ddist = dmask/sum(dmask)
    const float qm = (tid < LQ) ? qmask[(size_t)b * LQ + tid] : 0.f;
    const float dm = (tid < LD) ? dmask[(size_t)b * LD + tid] : 0.f;
    {
        float qs = qm, ds = dm;
#pragma unroll
        for (int s = 32; s; s >>= 1) {
            qs += __shfl_xor(qs, s);
            ds += __shfl_xor(ds, s);
        }
        if (lane == 0) { msum[0][wv] = qs; msum[1][wv] = ds; }
    }
    __syncthreads();   // msum ready (staging DMA may still be in flight)
    float qsum = 0.f, dsum = 0.f;
#pragma unroll
    for (int i = 0; i < 16; ++i) { qsum += msum[0][i]; dsum += msum[1][i]; }

    // Per-thread constants
    const float ddr = dm / dsum;           // ddist for this thread's column
    const float* qmb = qmask + (size_t)b * LQ + qbase + g;
    const float qd0 = qmb[0]  / qsum;
    const float qd1 = qmb[4]  / qsum;
    const float qd2 = qmb[8]  / qsum;
    const float qd3 = qmb[12] / qsum;

    __syncthreads();  // fences staging DMA + ulds/vs init
    const int nit = *nitp;

    // u-step per-lane K base: row (qbase+g), byte column m*8 (+ p*2048 + cb*128 imm)
    const unsigned char* ukp = &K8[qbase + g][m << 3];
    // v-step per-lane K base: row qbase, byte column lane*8 (+ k*512 imm)
    const unsigned char* vkp = &K8[qbase][d8];

    for (int it = 0; it < nit; ++it) {
        // ---- v-step partials: acc[d] = sum_{k=0..15} K[qbase+k][d]*u[k]
        float uvr = ulds[wv][m];   // lane holds u[qbase+m] (broadcast across groups)
        float a0 = 0.f, a1 = 0.f, a2 = 0.f, a3 = 0.f;
        float a4 = 0.f, a5 = 0.f, a6 = 0.f, a7 = 0.f;
        float usum = 0.f;
#pragma unroll
        for (int k = 0; k < 16; ++k) {
            const float uk = readlane_f(uvr, k);   // SGPR broadcast, no DS op
            usum += uk;
            const uint2 kw = *reinterpret_cast<const uint2*>(vkp + k * LD);
            a0 = fmaf(ub0(kw.x), uk, a0);
            a1 = fmaf(ub1(kw.x), uk, a1);
            a2 = fmaf(ub2(kw.x), uk, a2);
            a3 = fmaf(ub3(kw.x), uk, a3);
            a4 = fmaf(ub0(kw.y), uk, a4);
            a5 = fmaf(ub1(kw.y), uk, a5);
            a6 = fmaf(ub2(kw.y), uk, a6);
            a7 = fmaf(ub3(kw.y), uk, a7);
        }
        // affine correction: partial[d] = KOFF*usum + KSCL*acc8[d]
        const float ofs = KOFF * usum;
        a0 = fmaf(KSCL, a0, ofs); a1 = fmaf(KSCL, a1, ofs);
        a2 = fmaf(KSCL, a2, ofs); a3 = fmaf(KSCL, a3, ofs);
        a4 = fmaf(KSCL, a4, ofs); a5 = fmaf(KSCL, a5, ofs);
        a6 = fmaf(KSCL, a6, ofs); a7 = fmaf(KSCL, a7, ofs);

        // Phase A: waves 0-7 store partials.
        if (wv < 8) {
            *reinterpret_cast<float4*>(&part8[wv][d8])     = make_float4(a0, a1, a2, a3);
            *reinterpret_cast<float4*>(&part8[wv][d8 + 4]) = make_float4(a4, a5, a6, a7);
        }
        __syncthreads();
        // Phase B: waves 8-15 add theirs (1:1 mapping, no races).
        if (wv >= 8) {
            float4 p0 = *reinterpret_cast<const float4*>(&part8[wv - 8][d8]);
            float4 p1 = *reinterpret_cast<const float4*>(&part8[wv - 8][d8 + 4]);
            p0.x += a0; p0.y += a1; p0.z += a2; p0.w += a3;
            p1.x += a4; p1.y += a5; p1.z += a6; p1.w += a7;
            *reinterpret_cast<float4*>(&part8[wv - 8][d8])     = p0;
            *reinterpret_cast<float4*>(&part8[wv - 8][d8 + 4]) = p1;
        }
        __syncthreads();
        // Column sum + v = dd / colsum; convergence test vs previous v
        if (tid < LD) {
            float s = part8[0][tid] + part8[1][tid] + part8[2][tid] + part8[3][tid]
                    + part8[4][tid] + part8[5][tid] + part8[6][tid] + part8[7][tid];
            float old = vs[tid];
            float nv = ddr * __builtin_amdgcn_rcpf(s);
            vs[tid] = nv;
            bool bad = fabsf(nv - old) > 1e-6f * fabsf(nv);
            unsigned long long bm = __ballot(bad);
            if (lane == 0) cflag[wv] = (unsigned int)(bm != 0ull);
        }
        __syncthreads();

        // Uniform early exit: v reached fixed point -> u already consistent.
        unsigned int anybad = cflag[0] | cflag[1] | cflag[2] | cflag[3]
                            | cflag[4] | cflag[5] | cflag[6] | cflag[7];
        if (anybad == 0u) break;

        // ---- u-step: 16-lane group g owns row (qbase + p*4 + g) per pass p.
        // Lane m covers columns [cb*128 + m*8, +8) for cb = 0..3.
        float r0 = 0.f, r1 = 0.f, r2 = 0.f, r3 = 0.f;
        float vt = 0.f;
#pragma unroll
        for (int cb = 0; cb < 4; ++cb) {
            const float4 va = *reinterpret_cast<const float4*>(&vs[cb * 128 + (m << 3)]);
            const float4 vb = *reinterpret_cast<const float4*>(&vs[cb * 128 + (m << 3) + 4]);
            vt += ((va.x + va.y) + (va.z + va.w)) + ((vb.x + vb.y) + (vb.z + vb.w));
#define UPASS(P, RACC) { \
            const uint2 kw = *reinterpret_cast<const uint2*>(ukp + (P) * 2048 + cb * 128); \
            RACC = fmaf(ub0(kw.x), va.x, RACC); \
            RACC = fmaf(ub1(kw.x), va.y, RACC); \
            RACC = fmaf(ub2(kw.x), va.z, RACC); \
            RACC = fmaf(ub3(kw.x), va.w, RACC); \
            RACC = fmaf(ub0(kw.y), vb.x, RACC); \
            RACC = fmaf(ub1(kw.y), vb.y, RACC); \
            RACC = fmaf(ub2(kw.y), vb.z, RACC); \
            RACC = fmaf(ub3(kw.y), vb.w, RACC); }
            UPASS(0, r0)
            UPASS(1, r1)
            UPASS(2, r2)
            UPASS(3, r3)
#undef UPASS
        }
        // vsum: reduce vt within the 16-lane group (covers all 512 columns)
        vt += __shfl_xor(vt, 1);
        vt += __shfl_xor(vt, 2);
        vt += __shfl_xor(vt, 4);
        vt += __shfl_xor(vt, 8);
        const float vofs = KOFF * vt;
        // row-reduce all 4 accumulators with one 4-step butterfly set
        r0 += __shfl_xor(r0, 1); r1 += __shfl_xor(r1, 1);
        r2 += __shfl_xor(r2, 1); r3 += __shfl_xor(r3, 1);
        r0 += __shfl_xor(r0, 2); r1 += __shfl_xor(r1, 2);
        r2 += __shfl_xor(r2, 2); r3 += __shfl_xor(r3, 2);
        r0 += __shfl_xor(r0, 4); r1 += __shfl_xor(r1, 4);
        r2 += __shfl_xor(r2, 4); r3 += __shfl_xor(r3, 4);
        r0 += __shfl_xor(r0, 8); r1 += __shfl_xor(r1, 8);
        r2 += __shfl_xor(r2, 8); r3 += __shfl_xor(r3, 8);
        const float u0 = qd0 * __builtin_amdgcn_rcpf(fmaf(KSCL, r0, vofs));
        const float u1 = qd1 * __builtin_amdgcn_rcpf(fmaf(KSCL, r1, vofs));
        const float u2 = qd2 * __builtin_amdgcn_rcpf(fmaf(KSCL, r2, vofs));
        const float u3 = qd3 * __builtin_amdgcn_rcpf(fmaf(KSCL, r3, vofs));
        if (m == 0) {
            ulds[wv][g]      = u0;
            ulds[wv][4 + g]  = u1;
            ulds[wv][8 + g]  = u2;
            ulds[wv][12 + g] = u3;
        }
        // ulds[wv] is only read by its own wave (next v-step): intra-wave
        // lgkmcnt ordering suffices, no barrier. part8 next-iter writes are
        // fenced by the post-colsum barrier above.
    }

    __syncthreads();
    if (tid < LD) vout[(size_t)b * LD + tid] = (nit > 0) ? vs[tid] : 0.0f;
    if (tid < LQ) uout[(size_t)b * LQ + tid] = ulds[tid >> 4][tid & 15];
}

// ---------------------------------------------------------------------------
// Kernel: T = u*K*v, partial distances = sum(C*T) per (batch, chunk)
// grid (16, NB) = 1024 blocks (4 blocks/CU), 256 threads; K as affine u8.
// ---------------------------------------------------------------------------
#define TCHUNKS 16
__global__ __launch_bounds__(256) void tdist_kernel(const float* __restrict__ C,
                                                    const unsigned char* __restrict__ K,
                                                    const float* __restrict__ u,
                                                    const float* __restrict__ v,
                                                    float* __restrict__ T,
                                                    float* __restrict__ part) {
    const int b = blockIdx.y;
    const int ch = blockIdx.x;
    const int tid = threadIdx.x;
    __shared__ float us[LQ], vs[LD];
    us[tid] = u[(size_t)b * LQ + tid];
    vs[tid] = v[(size_t)b * LD + tid];
    vs[tid + 256] = v[(size_t)b * LD + 256 + tid];
    __syncthreads();

    const unsigned int* Kb4 = reinterpret_cast<const unsigned int*>(K + (size_t)b * CELEMS);
    const float4* Cb4 = reinterpret_cast<const float4*>(C + (size_t)b * CELEMS);
    float4* Tb4 = reinterpret_cast<float4*>(T + (size_t)b * CELEMS);

    float local = 0.f;
    const int chunk4 = CELEMS / (4 * TCHUNKS);  // 2048 uchar4-groups per chunk
    for (int i = tid; i < chunk4; i += 256) {
        int e4 = ch * chunk4 + i;
        int e = e4 << 2;
        int q = e >> 9;
        int dj = e & (LD - 1);   // 4 | 512 so all 4 elems share q
        unsigned int kw = Kb4[e4];
        float4 cv = Cb4[e4];
        float uq = us[q];
        float t0 = uq * fmaf(KSCL, ub0(kw), KOFF) * vs[dj];
        float t1 = uq * fmaf(KSCL, ub1(kw), KOFF) * vs[dj + 1];
        float t2 = uq * fmaf(KSCL, ub2(kw), KOFF) * vs[dj + 2];
        float t3 = uq * fmaf(KSCL, ub3(kw), KOFF) * vs[dj + 3];
        Tb4[e4] = make_float4(t0, t1, t2, t3);
        local += cv.x * t0 + cv.y * t1 + cv.z * t2 + cv.w * t3;
    }

    __shared__ float red[256];
    red[tid] = local;
    __syncthreads();
    for (int st = 128; st; st >>= 1) {
        if (tid < st) red[tid] += red[tid + st];
        __syncthreads();
    }
    if (tid == 0) part[b * TCHUNKS + ch] = red[0];
}

__global__ void final_dist_kernel(const float* __restrict__ part, float* __restrict__ dist) {
    int b = threadIdx.x;
    if (b < NB) {
        float s = 0.f;
#pragma unroll
        for (int i = 0; i < TCHUNKS; ++i) s += part[b * TCHUNKS + i];
        dist[b] = s;
    }
}

// ---------------------------------------------------------------------------
extern "C" void kernel_launch(void* const* d_in, const int* in_sizes, int n_in,
                              void* d_out, int out_size, void* d_ws, size_t ws_size,
                              hipStream_t stream) {
    const float* qe = (const float*)d_in[0];
    const float* qmask = (const float*)d_in[1];
    const float* de = (const float*)d_in[2];
    const float* dmask = (const float*)d_in[3];
    const int* nit = (const int*)d_in[4];

    float* out = (float*)d_out;
    float* dist = out;
    float* Cout = out + 64;
    float* Tout = out + 64 + CTOTAL;

    // Workspace layout
    char* ws = (char*)d_ws;
    size_t off = 0;
    unsigned char* Kw = (unsigned char*)(ws + off); off += CTOTAL;               // 8 MB u8
    unsigned int* cmax = (unsigned int*)(ws + off); off += NB * 4;
    float* uvec  = (float*)(ws + off); off += (size_t)QD_ELEMS * 4;
    float* vvec  = (float*)(ws + off); off += (size_t)DD_ELEMS * 4;
    float* part  = (float*)(ws + off); off += NB * TCHUNKS * 4;

    hipMemsetAsync(cmax, 0, NB * 4, stream);

    gemm_mfma_kernel<<<NB * 8, 256, 0, stream>>>(qe, de, Cout, cmax);

    expk_kernel<<<(CTOTAL / 4) / 256, 256, 0, stream>>>((const float4*)Cout, cmax, (unsigned int*)Kw);

    sinkhorn_kernel<<<NB, 1024, 0, stream>>>(Kw, qmask, dmask, nit, uvec, vvec);

    dim3 tgrid(TCHUNKS, NB);
    tdist_kernel<<<tgrid, 256, 0, stream>>>(Cout, Kw, uvec, vvec, Tout, part);

    final_dist_kernel<<<1, 64, 0, stream>>>(part, dist);
}

// Round 23
// 87.415 us; speedup vs baseline: 1.1607x; 1.1607x over previous
//
#include <hip/hip_runtime.h>
#include <hip/hip_bf16.h>
#include <cstdint>

// Problem constants (fixed shapes from the reference)
#define NB 64
#define LQ 256
#define LD 512
#define HD 768
#define QD_ELEMS (NB * LQ)          // 16384
#define DD_ELEMS (NB * LD)          // 32768
#define CELEMS   (LQ * LD)          // 131072 per batch
#define CTOTAL   ((size_t)NB * CELEMS)  // 8388608

// Affine u8 encoding of K = exp(-C/cmax) in [exp(-1), 1]:
//   k8 = round((K - KOFF) / KSCL),  K ~= KOFF + KSCL*k8
#define KOFF 0.36787944117f
#define KSCL ((1.0f - 0.36787944117f) / 255.0f)

typedef __attribute__((ext_vector_type(8))) short short8;
typedef __attribute__((ext_vector_type(16))) float f32x16;

// LLVM pattern-matches these to v_cvt_f32_ubyte0..3 on gfx9xx.
static __device__ __forceinline__ float ub0(unsigned int w) {
    return (float)(w & 0xffu);
}
static __device__ __forceinline__ float ub1(unsigned int w) {
    return (float)((w >> 8) & 0xffu);
}
static __device__ __forceinline__ float ub2(unsigned int w) {
    return (float)((w >> 16) & 0xffu);
}
static __device__ __forceinline__ float ub3(unsigned int w) {
    return (float)(w >> 24);
}
static __device__ __forceinline__ float readlane_f(float v, int l) {
    return __uint_as_float((unsigned int)__builtin_amdgcn_readlane((int)__float_as_uint(v), l));
}
// f32 -> bf16 round-to-nearest-even (bit trick; inputs are finite)
static __device__ __forceinline__ unsigned short f2bf(float f) {
    unsigned int u = __float_as_uint(f);
    u += 0x7fff + ((u >> 16) & 1);
    return (unsigned short)(u >> 16);
}

// ---------------------------------------------------------------------------
// Kernel: batched GEMM via bf16 MFMA with FUSED row norms.
// C[b,q,d] = 1 - (qe[b,q,:].de[b,d,:]) * qinv*dinv, + per-batch max (atomic).
// 128x128 tile, 4 waves (2x2), wave tile 64x64 = 4x mfma_f32_32x32x16_bf16.
// Grid: wgid = t*64 + b => all 8 tiles of a batch pinned to one XCD.
// Lever search CLOSED: 64x128 tiles (R20, +18us), unpinned grid (R16, +16us),
// expk fusion (R18, +13us), double-buffer (R22, +14us: LDS 74KB -> 1 block/CU,
// FETCH 74->123MB). This single-buffer 128^2 + pinning config is the optimum.
// LDS XOR-swizzle (byte ^= (row&7)<<4) kills the 128B-stride bank conflict.
// ---------------------------------------------------------------------------
__global__ __launch_bounds__(256) void gemm_mfma_kernel(
        const float* __restrict__ qe,
        const float* __restrict__ de,
        float* __restrict__ Cout,
        unsigned int* __restrict__ cmax) {
    const int wgid = blockIdx.x;
    const int b = wgid & 63;         // batch pinned to XCD (wgid%8 == b%8)
    const int t = wgid >> 6;
    const int m0 = (t >> 2) * 128;   // q-tile base (2 tiles)
    const int n0 = (t & 3) * 128;    // d-tile base (4 tiles)
    const int tid = threadIdx.x;
    const int wv = tid >> 6;
    const int lane = tid & 63;
    const int wm = (wv >> 1) * 64;
    const int wn = (wv & 1) * 64;

    __shared__ __align__(16) unsigned char As[128 * 128];  // 128 rows x 64 bf16
    __shared__ __align__(16) unsigned char Bs[128 * 128];
    __shared__ float sq_l[2][128][8];                      // norm partials, 8 KB
    __shared__ float qinv_s[128], dinv_s[128];

    const float* Ag = qe + (size_t)b * LQ * HD + (size_t)m0 * HD;
    const float* Bg = de + (size_t)b * LD * HD + (size_t)n0 * HD;

    f32x16 acc00, acc01, acc10, acc11;
#pragma unroll
    for (int i = 0; i < 16; ++i) {
        acc00[i] = 0.f; acc01[i] = 0.f; acc10[i] = 0.f; acc11[i] = 0.f;
    }
    float asq0 = 0.f, asq1 = 0.f, asq2 = 0.f, asq3 = 0.f;
    float bsq0 = 0.f, bsq1 = 0.f, bsq2 = 0.f, bsq3 = 0.f;

    for (int k0 = 0; k0 < HD; k0 += 64) {
        __syncthreads();   // previous substep's frag reads done before overwrite
#pragma unroll
        for (int h = 0; h < 4; ++h) {
            int idx = tid + h * 256;   // 0..1023
            int r = idx >> 3;          // row 0..127
            int c = idx & 7;           // 16B chunk (8 bf16 = 8 f32)
            const float* ap = Ag + (size_t)r * HD + k0 + c * 8;
            const float* bp = Bg + (size_t)r * HD + k0 + c * 8;
            float4 a0 = *reinterpret_cast<const float4*>(ap);
            float4 a1 = *reinterpret_cast<const float4*>(ap + 4);
            float4 b0 = *reinterpret_cast<const float4*>(bp);
            float4 b1 = *reinterpret_cast<const float4*>(bp + 4);
            float as = a0.x * a0.x + a0.y * a0.y + a0.z * a0.z + a0.w * a0.w
                     + a1.x * a1.x + a1.y * a1.y + a1.z * a1.z + a1.w * a1.w;
            float bs = b0.x * b0.x + b0.y * b0.y + b0.z * b0.z + b0.w * b0.w
                     + b1.x * b1.x + b1.y * b1.y + b1.z * b1.z + b1.w * b1.w;
            if (h == 0) { asq0 += as; bsq0 += bs; }
            else if (h == 1) { asq1 += as; bsq1 += bs; }
            else if (h == 2) { asq2 += as; bsq2 += bs; }
            else { asq3 += as; bsq3 += bs; }
            short8 av, bv;
            av[0] = (short)f2bf(a0.x); av[1] = (short)f2bf(a0.y);
            av[2] = (short)f2bf(a0.z); av[3] = (short)f2bf(a0.w);
            av[4] = (short)f2bf(a1.x); av[5] = (short)f2bf(a1.y);
            av[6] = (short)f2bf(a1.z); av[7] = (short)f2bf(a1.w);
            bv[0] = (short)f2bf(b0.x); bv[1] = (short)f2bf(b0.y);
            bv[2] = (short)f2bf(b0.z); bv[3] = (short)f2bf(b0.w);
            bv[4] = (short)f2bf(b1.x); bv[5] = (short)f2bf(b1.y);
            bv[6] = (short)f2bf(b1.z); bv[7] = (short)f2bf(b1.w);
            int byteoff = (r * 128 + c * 16) ^ ((r & 7) << 4);
            *reinterpret_cast<short8*>(As + byteoff) = av;
            *reinterpret_cast<short8*>(Bs + byteoff) = bv;
        }
        __syncthreads();

        const int hi = lane >> 5;
        const int la = lane & 31;
#pragma unroll
        for (int ks = 0; ks < 4; ++ks) {
            int ra0 = wm + la, ra1 = wm + 32 + la;
            int rb0 = wn + la, rb1 = wn + 32 + la;
            short8 af0 = *reinterpret_cast<const short8*>(
                As + ((ra0 * 128 + ks * 32 + hi * 16) ^ ((ra0 & 7) << 4)));
            short8 af1 = *reinterpret_cast<const short8*>(
                As + ((ra1 * 128 + ks * 32 + hi * 16) ^ ((ra1 & 7) << 4)));
            short8 bf0 = *reinterpret_cast<const short8*>(
                Bs + ((rb0 * 128 + ks * 32 + hi * 16) ^ ((rb0 & 7) << 4)));
            short8 bf1 = *reinterpret_cast<const short8*>(
                Bs + ((rb1 * 128 + ks * 32 + hi * 16) ^ ((rb1 & 7) << 4)));
            acc00 = __builtin_amdgcn_mfma_f32_32x32x16_bf16(af0, bf0, acc00, 0, 0, 0);
            acc01 = __builtin_amdgcn_mfma_f32_32x32x16_bf16(af0, bf1, acc01, 0, 0, 0);
            acc10 = __builtin_amdgcn_mfma_f32_32x32x16_bf16(af1, bf0, acc10, 0, 0, 0);
            acc11 = __builtin_amdgcn_mfma_f32_32x32x16_bf16(af1, bf1, acc11, 0, 0, 0);
        }
    }

    // Norm reduction: thread owns 4 fixed (r,c) pairs (idx = tid + h*256)
#pragma unroll
    for (int h = 0; h < 4; ++h) {
        int idx = tid + h * 256;
        int r = idx >> 3, c = idx & 7;
        float as = (h == 0) ? asq0 : (h == 1) ? asq1 : (h == 2) ? asq2 : asq3;
        float bs = (h == 0) ? bsq0 : (h == 1) ? bsq1 : (h == 2) ? bsq2 : bsq3;
        sq_l[0][r][c] = as;
        sq_l[1][r][c] = bs;
    }
    __syncthreads();
    if (tid < 128) {
        float s = sq_l[0][tid][0] + sq_l[0][tid][1] + sq_l[0][tid][2] + sq_l[0][tid][3]
                + sq_l[0][tid][4] + sq_l[0][tid][5] + sq_l[0][tid][6] + sq_l[0][tid][7];
        qinv_s[tid] = 1.0f / fmaxf(sqrtf(s), 1e-12f);
    } else {
        int r = tid - 128;
        float s = sq_l[1][r][0] + sq_l[1][r][1] + sq_l[1][r][2] + sq_l[1][r][3]
                + sq_l[1][r][4] + sq_l[1][r][5] + sq_l[1][r][6] + sq_l[1][r][7];
        dinv_s[r] = 1.0f / fmaxf(sqrtf(s), 1e-12f);
    }
    __syncthreads();

    // Epilogue: C/D layout col=lane&31, row=(reg&3)+8*(reg>>2)+4*(lane>>5)
    float lmax = -1e30f;
    float* Cb = Cout + (size_t)b * CELEMS;
    const int la = lane & 31;
    const int hi4 = (lane >> 5) * 4;
#define EPI(ACC, P, Q) { \
    int col = wn + (Q) * 32 + la; \
    float dv = dinv_s[col]; \
    _Pragma("unroll") \
    for (int i = 0; i < 16; ++i) { \
        int row = wm + (P) * 32 + (i & 3) + 8 * (i >> 2) + hi4; \
        float c = 1.0f - ACC[i] * qinv_s[row] * dv; \
        Cb[(size_t)(m0 + row) * LD + n0 + col] = c; \
        lmax = fmaxf(lmax, c); \
    } }
    EPI(acc00, 0, 0)
    EPI(acc01, 0, 1)
    EPI(acc10, 1, 0)
    EPI(acc11, 1, 1)
#undef EPI

    __shared__ float red[256];
    red[tid] = lmax;
    __syncthreads();
    for (int st = 128; st; st >>= 1) {
        if (tid < st) red[tid] = fmaxf(red[tid], red[tid + st]);
        __syncthreads();
    }
    if (tid == 0) atomicMax(cmax + b, __float_as_uint(red[0]));
}

// ---------------------------------------------------------------------------
// Kernel: K = exp(-C / cmax) quantized to affine u8 (4 elems/thread)
// Full-chip parallel (8192 blocks).
// ---------------------------------------------------------------------------
__global__ __launch_bounds__(256) void expk_kernel(const float4* __restrict__ C4,
                                                   const unsigned int* __restrict__ cmax,
                                                   unsigned int* __restrict__ K4) {
    size_t t = (size_t)blockIdx.x * 256 + threadIdx.x;  // 2097152 total
    int b = (int)(t >> 15);
    float inv = -1.0f / __uint_as_float(cmax[b]);
    const float sc = 1.0f / KSCL;
    float4 c = C4[t];
    float q0 = fminf(fmaxf((expf(c.x * inv) - KOFF) * sc, 0.f), 255.f);
    float q1 = fminf(fmaxf((expf(c.y * inv) - KOFF) * sc, 0.f), 255.f);
    float q2 = fminf(fmaxf((expf(c.z * inv) - KOFF) * sc, 0.f), 255.f);
    float q3 = fminf(fmaxf((expf(c.w * inv) - KOFF) * sc, 0.f), 255.f);
    unsigned int i0 = (unsigned int)(q0 + 0.5f);
    unsigned int i1 = (unsigned int)(q1 + 0.5f);
    unsigned int i2 = (unsigned int)(q2 + 0.5f);
    unsigned int i3 = (unsigned int)(q3 + 0.5f);
    K4[t] = i0 | (i1 << 8) | (i2 << 16) | (i3 << 24);
}

// ---------------------------------------------------------------------------
// Kernel: persistent Sinkhorn — one workgroup per batch, nit iterations.
// Whole-batch K as affine-u8 in LDS (128 KB); convergence early-exit
// (v fixed point, rel tol 1e-6); mask->distribution fused into prologue
// (K-staging DMA issued first so HBM latency hides under mask reduction).
// ---------------------------------------------------------------------------
__global__ __launch_bounds__(1024) __attribute__((amdgpu_waves_per_eu(4, 4)))
void sinkhorn_kernel(
        const unsigned char* __restrict__ Kmat,
        const float* __restrict__ qmask,
        const float* __restrict__ dmask,
        const int* __restrict__ nitp,
        float* __restrict__ uout,
        float* __restrict__ vout) {
    const int b = blockIdx.x;
    const int tid = threadIdx.x;
    const int wv = tid >> 6;       // wave 0..15
    const int lane = tid & 63;
    const int d8 = lane << 3;      // v-step column base (0..504)
    const int qbase = wv << 4;     // row base (0..240)
    const int g = lane >> 4;       // 16-lane group 0..3 (u-step row within pass)
    const int m = lane & 15;       // position within group

    __shared__ unsigned char K8[LQ][LD];   // 128 KB whole-batch K
    __shared__ float part8[8][LD];         // 16 KB partials
    __shared__ float vs[LD];               // 2 KB
    __shared__ float ulds[16][16];         // 1 KB  u[wave][row]
    __shared__ unsigned int cflag[8];      // per-wave convergence flags
    __shared__ float msum[2][16];          // mask-sum partials

    // Issue whole-batch K staging (128 KB) HBM/L2 -> LDS first (no VGPR
    // transit); its latency hides under the mask reduction below.
    {
        const unsigned char* Kg = Kmat + (size_t)b * CELEMS;
        unsigned char* lb = &K8[0][0];
#pragma unroll
        for (int j = 0; j < 8; ++j) {
            __builtin_amdgcn_global_load_lds(
                (const __attribute__((address_space(1))) unsigned int*)
                    (Kg + (size_t)wv * 8192 + j * 1024 + lane * 16),
                (__attribute__((address_space(3))) unsigned int*)
                    (lb + wv * 8192 + j * 1024),
                16, 0, 0);
        }
    }

    if (tid < LQ) ulds[tid >> 4][tid & 15] = 1.0f;
    if (tid < LD) vs[tid] = 0.f;           // "previous v" for 1st iteration

    // ---- fused mass: qdist = qmask/sum(qmask), ddist = dmask/sum(dmask)
    const float qm = (tid < LQ) ? qmask[(size_t)b * LQ + tid] : 0.f;
    const float dm = (tid < LD) ? dmask[(size_t)b * LD + tid] : 0.f;
    {
        float qs = qm, ds = dm;
#pragma unroll
        for (int s = 32; s; s >>= 1) {
            qs += __shfl_xor(qs, s);
            ds += __shfl_xor(ds, s);
        }
        if (lane == 0) { msum[0][wv] = qs; msum[1][wv] = ds; }
    }
    __syncthreads();   // msum ready (staging DMA may still be in flight)
    float qsum = 0.f, dsum = 0.f;
#pragma unroll
    for (int i = 0; i < 16; ++i) { qsum += msum[0][i]; dsum += msum[1][i]; }

    // Per-thread constants
    const float ddr = dm / dsum;           // ddist for this thread's column
    const float* qmb = qmask + (size_t)b * LQ + qbase + g;
    const float qd0 = qmb[0]  / qsum;
    const float qd1 = qmb[4]  / qsum;
    const float qd2 = qmb[8]  / qsum;
    const float qd3 = qmb[12] / qsum;

    __syncthreads();  // fences staging DMA + ulds/vs init
    const int nit = *nitp;

    // u-step per-lane K base: row (qbase+g), byte column m*8 (+ p*2048 + cb*128 imm)
    const unsigned char* ukp = &K8[qbase + g][m << 3];
    // v-step per-lane K base: row qbase, byte column lane*8 (+ k*512 imm)
    const unsigned char* vkp = &K8[qbase][d8];

    for (int it = 0; it < nit; ++it) {
        // ---- v-step partials: acc[d] = sum_{k=0..15} K[qbase+k][d]*u[k]
        float uvr = ulds[wv][m];   // lane holds u[qbase+m] (broadcast across groups)
        float a0 = 0.f, a1 = 0.f, a2 = 0.f, a3 = 0.f;
        float a4 = 0.f, a5 = 0.f, a6 = 0.f, a7 = 0.f;
        float usum = 0.f;
#pragma unroll
        for (int k = 0; k < 16; ++k) {
            const float uk = readlane_f(uvr, k);   // SGPR broadcast, no DS op
            usum += uk;
            const uint2 kw = *reinterpret_cast<const uint2*>(vkp + k * LD);
            a0 = fmaf(ub0(kw.x), uk, a0);
            a1 = fmaf(ub1(kw.x), uk, a1);
            a2 = fmaf(ub2(kw.x), uk, a2);
            a3 = fmaf(ub3(kw.x), uk, a3);
            a4 = fmaf(ub0(kw.y), uk, a4);
            a5 = fmaf(ub1(kw.y), uk, a5);
            a6 = fmaf(ub2(kw.y), uk, a6);
            a7 = fmaf(ub3(kw.y), uk, a7);
        }
        // affine correction: partial[d] = KOFF*usum + KSCL*acc8[d]
        const float ofs = KOFF * usum;
        a0 = fmaf(KSCL, a0, ofs); a1 = fmaf(KSCL, a1, ofs);
        a2 = fmaf(KSCL, a2, ofs); a3 = fmaf(KSCL, a3, ofs);
        a4 = fmaf(KSCL, a4, ofs); a5 = fmaf(KSCL, a5, ofs);
        a6 = fmaf(KSCL, a6, ofs); a7 = fmaf(KSCL, a7, ofs);

        // Phase A: waves 0-7 store partials.
        if (wv < 8) {
            *reinterpret_cast<float4*>(&part8[wv][d8])     = make_float4(a0, a1, a2, a3);
            *reinterpret_cast<float4*>(&part8[wv][d8 + 4]) = make_float4(a4, a5, a6, a7);
        }
        __syncthreads();
        // Phase B: waves 8-15 add theirs (1:1 mapping, no races).
        if (wv >= 8) {
            float4 p0 = *reinterpret_cast<const float4*>(&part8[wv - 8][d8]);
            float4 p1 = *reinterpret_cast<const float4*>(&part8[wv - 8][d8 + 4]);
            p0.x += a0; p0.y += a1; p0.z += a2; p0.w += a3;
            p1.x += a4; p1.y += a5; p1.z += a6; p1.w += a7;
            *reinterpret_cast<float4*>(&part8[wv - 8][d8])     = p0;
            *reinterpret_cast<float4*>(&part8[wv - 8][d8 + 4]) = p1;
        }
        __syncthreads();
        // Column sum + v = dd / colsum; convergence test vs previous v
        if (tid < LD) {
            float s = part8[0][tid] + part8[1][tid] + part8[2][tid] + part8[3][tid]
                    + part8[4][tid] + part8[5][tid] + part8[6][tid] + part8[7][tid];
            float old = vs[tid];
            float nv = ddr * __builtin_amdgcn_rcpf(s);
            vs[tid] = nv;
            bool bad = fabsf(nv - old) > 1e-6f * fabsf(nv);
            unsigned long long bm = __ballot(bad);
            if (lane == 0) cflag[wv] = (unsigned int)(bm != 0ull);
        }
        __syncthreads();

        // Uniform early exit: v reached fixed point -> u already consistent.
        unsigned int anybad = cflag[0] | cflag[1] | cflag[2] | cflag[3]
                            | cflag[4] | cflag[5] | cflag[6] | cflag[7];
        if (anybad == 0u) break;

        // ---- u-step: 16-lane group g owns row (qbase + p*4 + g) per pass p.
        // Lane m covers columns [cb*128 + m*8, +8) for cb = 0..3.
        float r0 = 0.f, r1 = 0.f, r2 = 0.f, r3 = 0.f;
        float vt = 0.f;
#pragma unroll
        for (int cb = 0; cb < 4; ++cb) {
            const float4 va = *reinterpret_cast<const float4*>(&vs[cb * 128 + (m << 3)]);
            const float4 vb = *reinterpret_cast<const float4*>(&vs[cb * 128 + (m << 3) + 4]);
            vt += ((va.x + va.y) + (va.z + va.w)) + ((vb.x + vb.y) + (vb.z + vb.w));
#define UPASS(P, RACC) { \
            const uint2 kw = *reinterpret_cast<const uint2*>(ukp + (P) * 2048 + cb * 128); \
            RACC = fmaf(ub0(kw.x), va.x, RACC); \
            RACC = fmaf(ub1(kw.x), va.y, RACC); \
            RACC = fmaf(ub2(kw.x), va.z, RACC); \
            RACC = fmaf(ub3(kw.x), va.w, RACC); \
            RACC = fmaf(ub0(kw.y), vb.x, RACC); \
            RACC = fmaf(ub1(kw.y), vb.y, RACC); \
            RACC = fmaf(ub2(kw.y), vb.z, RACC); \
            RACC = fmaf(ub3(kw.y), vb.w, RACC); }
            UPASS(0, r0)
            UPASS(1, r1)
            UPASS(2, r2)
            UPASS(3, r3)
#undef UPASS
        }
        // vsum: reduce vt within the 16-lane group (covers all 512 columns)
        vt += __shfl_xor(vt, 1);
        vt += __shfl_xor(vt, 2);
        vt += __shfl_xor(vt, 4);
        vt += __shfl_xor(vt, 8);
        const float vofs = KOFF * vt;
        // row-reduce all 4 accumulators with one 4-step butterfly set
        r0 += __shfl_xor(r0, 1); r1 += __shfl_xor(r1, 1);
        r2 += __shfl_xor(r2, 1); r3 += __shfl_xor(r3, 1);
        r0 += __shfl_xor(r0, 2); r1 += __shfl_xor(r1, 2);
        r2 += __shfl_xor(r2, 2); r3 += __shfl_xor(r3, 2);
        r0 += __shfl_xor(r0, 4); r1 += __shfl_xor(r1, 4);
        r2 += __shfl_xor(r2, 4); r3 += __shfl_xor(r3, 4);
        r0 += __shfl_xor(r0, 8); r1 += __shfl_xor(r1, 8);
        r2 += __shfl_xor(r2, 8); r3 += __shfl_xor(r3, 8);
        const float u0 = qd0 * __builtin_amdgcn_rcpf(fmaf(KSCL, r0, vofs));
        const float u1 = qd1 * __builtin_amdgcn_rcpf(fmaf(KSCL, r1, vofs));
        const float u2 = qd2 * __builtin_amdgcn_rcpf(fmaf(KSCL, r2, vofs));
        const float u3 = qd3 * __builtin_amdgcn_rcpf(fmaf(KSCL, r3, vofs));
        if (m == 0) {
            ulds[wv][g]      = u0;
            ulds[wv][4 + g]  = u1;
            ulds[wv][8 + g]  = u2;
            ulds[wv][12 + g] = u3;
        }
        // ulds[wv] is only read by its own wave (next v-step): intra-wave
        // lgkmcnt ordering suffices, no barrier. part8 next-iter writes are
        // fenced by the post-colsum barrier above.
    }

    __syncthreads();
    if (tid < LD) vout[(size_t)b * LD + tid] = (nit > 0) ? vs[tid] : 0.0f;
    if (tid < LQ) uout[(size_t)b * LQ + tid] = ulds[tid >> 4][tid & 15];
}

// ---------------------------------------------------------------------------
// Kernel: T = u*K*v, partial distances = sum(C*T) per (batch, chunk)
// grid (16, NB) = 1024 blocks (4 blocks/CU), 256 threads; K as affine u8.
// ---------------------------------------------------------------------------
#define TCHUNKS 16
__global__ __launch_bounds__(256) void tdist_kernel(const float* __restrict__ C,
                                                    const unsigned char* __restrict__ K,
                                                    const float* __restrict__ u,
                                                    const float* __restrict__ v,
                                                    float* __restrict__ T,
                                                    float* __restrict__ part) {
    const int b = blockIdx.y;
    const int ch = blockIdx.x;
    const int tid = threadIdx.x;
    __shared__ float us[LQ], vs[LD];
    us[tid] = u[(size_t)b * LQ + tid];
    vs[tid] = v[(size_t)b * LD + tid];
    vs[tid + 256] = v[(size_t)b * LD + 256 + tid];
    __syncthreads();

    const unsigned int* Kb4 = reinterpret_cast<const unsigned int*>(K + (size_t)b * CELEMS);
    const float4* Cb4 = reinterpret_cast<const float4*>(C + (size_t)b * CELEMS);
    float4* Tb4 = reinterpret_cast<float4*>(T + (size_t)b * CELEMS);

    float local = 0.f;
    const int chunk4 = CELEMS / (4 * TCHUNKS);  // 2048 uchar4-groups per chunk
    for (int i = tid; i < chunk4; i += 256) {
        int e4 = ch * chunk4 + i;
        int e = e4 << 2;
        int q = e >> 9;
        int dj = e & (LD - 1);   // 4 | 512 so all 4 elems share q
        unsigned int kw = Kb4[e4];
        float4 cv = Cb4[e4];
        float uq = us[q];
        float t0 = uq * fmaf(KSCL, ub0(kw), KOFF) * vs[dj];
        float t1 = uq * fmaf(KSCL, ub1(kw), KOFF) * vs[dj + 1];
        float t2 = uq * fmaf(KSCL, ub2(kw), KOFF) * vs[dj + 2];
        float t3 = uq * fmaf(KSCL, ub3(kw), KOFF) * vs[dj + 3];
        Tb4[e4] = make_float4(t0, t1, t2, t3);
        local += cv.x * t0 + cv.y * t1 + cv.z * t2 + cv.w * t3;
    }

    __shared__ float red[256];
    red[tid] = local;
    __syncthreads();
    for (int st = 128; st; st >>= 1) {
        if (tid < st) red[tid] += red[tid + st];
        __syncthreads();
    }
    if (tid == 0) part[b * TCHUNKS + ch] = red[0];
}

__global__ void final_dist_kernel(const float* __restrict__ part, float* __restrict__ dist) {
    int b = threadIdx.x;
    if (b < NB) {
        float s = 0.f;
#pragma unroll
        for (int i = 0; i < TCHUNKS; ++i) s += part[b * TCHUNKS + i];
        dist[b] = s;
    }
}

// ---------------------------------------------------------------------------
extern "C" void kernel_launch(void* const* d_in, const int* in_sizes, int n_in,
                              void* d_out, int out_size, void* d_ws, size_t ws_size,
                              hipStream_t stream) {
    const float* qe = (const float*)d_in[0];
    const float* qmask = (const float*)d_in[1];
    const float* de = (const float*)d_in[2];
    const float* dmask = (const float*)d_in[3];
    const int* nit = (const int*)d_in[4];

    float* out = (float*)d_out;
    float* dist = out;
    float* Cout = out + 64;
    float* Tout = out + 64 + CTOTAL;

    // Workspace layout
    char* ws = (char*)d_ws;
    size_t off = 0;
    unsigned char* Kw = (unsigned char*)(ws + off); off += CTOTAL;               // 8 MB u8
    unsigned int* cmax = (unsigned int*)(ws + off); off += NB * 4;
    float* uvec  = (float*)(ws + off); off += (size_t)QD_ELEMS * 4;
    float* vvec  = (float*)(ws + off); off += (size_t)DD_ELEMS * 4;
    float* part  = (float*)(ws + off); off += NB * TCHUNKS * 4;

    hipMemsetAsync(cmax, 0, NB * 4, stream);

    gemm_mfma_kernel<<<NB * 8, 256, 0, stream>>>(qe, de, Cout, cmax);

    expk_kernel<<<(CTOTAL / 4) / 256, 256, 0, stream>>>((const float4*)Cout, cmax, (unsigned int*)Kw);

    sinkhorn_kernel<<<NB, 1024, 0, stream>>>(Kw, qmask, dmask, nit, uvec, vvec);

    dim3 tgrid(TCHUNKS, NB);
    tdist_kernel<<<tgrid, 256, 0, stream>>>(Cout, Kw, uvec, vvec, Tout, part);

    final_dist_kernel<<<1, 64, 0, stream>>>(part, dist);
}